// Round 1
// baseline (2729.574 us; speedup 1.0000x reference)
//
#include <hip/hip_runtime.h>
#include <math.h>

#define N_NODES 10000
#define N_EDGES 80000
#define N_ORI   12
#define IN_DIM  16
#define CDIM    64
#define HID     256
#define N_GRAPHS 16

__device__ __forceinline__ float gelu_f(float x) {
    return 0.5f * x * (1.0f + erff(x * 0.70710678118654752440f));
}

// ---------------------------------------------------------------------------
// K1: kb_ori MLP + fk[l][p][o][c] = (kb_ori @ Wf[l]).  144 blocks x 64.
// attr_ori[p][o] = ori[p].ori[o] (symmetric); poly feats [s, s^2, s^3, s^4].
// ---------------------------------------------------------------------------
__global__ __launch_bounds__(64) void ori_kernel(
    const float* __restrict__ ori, const float* __restrict__ Wo1,
    const float* __restrict__ bo1, const float* __restrict__ Wo2,
    const float* __restrict__ bo2, const float* __restrict__ Wf,
    float* __restrict__ fkb)
{
    __shared__ float sh[64];
    __shared__ float skb[64];
    int i = blockIdx.x / 12, j = blockIdx.x % 12;   // i=p, j=o
    int lane = threadIdx.x;
    float s = ori[3*i]*ori[3*j] + ori[3*i+1]*ori[3*j+1] + ori[3*i+2]*ori[3*j+2];
    float p1 = s, p2 = s*s, p3 = p2*s, p4 = p3*s;
    float acc = bo1[lane] + p1*Wo1[lane] + p2*Wo1[64+lane] + p3*Wo1[128+lane] + p4*Wo1[192+lane];
    sh[lane] = gelu_f(acc);
    __syncthreads();
    float acc2 = bo2[lane];
    #pragma unroll
    for (int k = 0; k < 64; k++) acc2 += sh[k] * Wo2[k*64 + lane];
    skb[lane] = gelu_f(acc2);
    __syncthreads();
    for (int l = 0; l < 2; l++) {
        float a = 0.f;
        #pragma unroll
        for (int k = 0; k < 64; k++) a += skb[k] * Wf[l*4096 + k*64 + lane];
        fkb[l*9216 + i*768 + j*64 + lane] = a;
    }
}

// ---------------------------------------------------------------------------
// K2: x = f @ We   (10000,16)@(16,64).  Wave per node.
// ---------------------------------------------------------------------------
__global__ __launch_bounds__(256) void embed_kernel(
    const float* __restrict__ f, const float* __restrict__ We, float* __restrict__ xe)
{
    int v = blockIdx.x*4 + (threadIdx.x >> 6);
    int lane = threadIdx.x & 63;
    if (v >= N_NODES) return;
    float acc = 0.f;
    #pragma unroll
    for (int k = 0; k < 16; k++) acc += f[v*16 + k] * We[k*64 + lane];
    xe[v*64 + lane] = acc;
}

// ---------------------------------------------------------------------------
// K3: per-edge: recompute kb (30->64->64 MLP * cutoff), msg = x[src]*(kb@Wk),
// atomic scatter into x1[dst,o,c].  Wave per edge, lane = channel.
// Weight COLUMNS live in VGPRs; cross-lane h1/kb go through per-wave LDS with
// uniform b128 broadcast reads (LDS-pipe cheap).
// ---------------------------------------------------------------------------
__global__ __launch_bounds__(256) void edge_kernel(
    const float* __restrict__ pos, const float* __restrict__ ori,
    const float* __restrict__ Wb1, const float* __restrict__ bb1,
    const float* __restrict__ Wb2, const float* __restrict__ bb2,
    const float* __restrict__ Wk, const int* __restrict__ ei,
    const float* __restrict__ x_in, float* __restrict__ x1,
    int has_ori)
{
    __shared__ float sh1[4][64];
    __shared__ float skb[4][64];
    __shared__ float sori[36];
    if (threadIdx.x < 36) sori[threadIdx.x] = ori[threadIdx.x];
    int w = threadIdx.x >> 6, lane = threadIdx.x & 63;

    float wb1c[30], wb2c[64], wkc[64];
    #pragma unroll
    for (int k = 0; k < 30; k++) wb1c[k] = Wb1[k*64 + lane];
    #pragma unroll
    for (int k = 0; k < 64; k++) wb2c[k] = Wb2[k*64 + lane];
    #pragma unroll
    for (int k = 0; k < 64; k++) wkc[k]  = Wk[k*64 + lane];
    float bb1l = bb1[lane], bb2l = bb2[lane];

    int e  = blockIdx.x*4 + w;                  // grid = 20000 exactly covers 80000
    int sn = ei[e], dn = ei[N_EDGES + e];
    float rx = pos[sn*3+0] - pos[dn*3+0];
    float ry = pos[sn*3+1] - pos[dn*3+1];
    float rz = pos[sn*3+2] - pos[dn*3+2];
    float d  = sqrtf(rx*rx + ry*ry + rz*rz);
    float u2 = d*d, u4 = u2*u2, u6 = u4*u2;
    float env = (d < 1.0f) ? (1.0f - 28.0f*u6 + 48.0f*u6*d - 21.0f*u6*u2) : 0.0f;
    const float* xsrc  = x_in + (has_ori ? (size_t)sn*768 : (size_t)sn*64);
    float*       x1row = x1 + (size_t)dn*768;
    __syncthreads();

    for (int o = 0; o < N_ORI; o++) {
        float ox = sori[3*o], oy = sori[3*o+1], oz = sori[3*o+2];
        float a  = rx*ox + ry*oy + rz*oz;
        float qx = rx - a*ox, qy = ry - a*oy, qz = rz - a*oz;
        float b  = sqrtf(qx*qx + qy*qy + qz*qz);
        // poly features of (a,b), degree 3 -> 30 dims, fused with layer-1 FMA
        float acc = bb1l + a*wb1c[0] + b*wb1c[1];
        float c0 = a*a, c1 = a*b, c2 = b*a, c3 = b*b;
        acc += c0*wb1c[2] + c1*wb1c[3] + c2*wb1c[4] + c3*wb1c[5];
        float d0=c0*a,d1=c0*b,d2=c1*a,d3=c1*b,d4=c2*a,d5=c2*b,d6=c3*a,d7=c3*b;
        acc += d0*wb1c[6]+d1*wb1c[7]+d2*wb1c[8]+d3*wb1c[9]
             + d4*wb1c[10]+d5*wb1c[11]+d6*wb1c[12]+d7*wb1c[13];
        acc += d0*a*wb1c[14]+d0*b*wb1c[15]+d1*a*wb1c[16]+d1*b*wb1c[17]
             + d2*a*wb1c[18]+d2*b*wb1c[19]+d3*a*wb1c[20]+d3*b*wb1c[21]
             + d4*a*wb1c[22]+d4*b*wb1c[23]+d5*a*wb1c[24]+d5*b*wb1c[25]
             + d6*a*wb1c[26]+d6*b*wb1c[27]+d7*a*wb1c[28]+d7*b*wb1c[29];
        sh1[w][lane] = gelu_f(acc);
        __syncthreads();
        float acc2 = bb2l;
        const float4* h4 = (const float4*)(&sh1[w][0]);
        #pragma unroll
        for (int k4 = 0; k4 < 16; k4++) {
            float4 hv = h4[k4];
            acc2 += hv.x*wb2c[4*k4] + hv.y*wb2c[4*k4+1] + hv.z*wb2c[4*k4+2] + hv.w*wb2c[4*k4+3];
        }
        skb[w][lane] = gelu_f(acc2) * env;
        __syncthreads();
        float accm = 0.f;
        const float4* kb4 = (const float4*)(&skb[w][0]);
        #pragma unroll
        for (int k4 = 0; k4 < 16; k4++) {
            float4 kv = kb4[k4];
            accm += kv.x*wkc[4*k4] + kv.y*wkc[4*k4+1] + kv.z*wkc[4*k4+2] + kv.w*wkc[4*k4+3];
        }
        float xs = has_ori ? xsrc[o*64 + lane] : xsrc[lane];
        atomicAdd(&x1row[o*64 + lane], xs * accm);
        __syncthreads();   // sh1/skb reuse next o; uniform trip count across waves
    }
}

// ---------------------------------------------------------------------------
// K4: per-row (row=v*12+p): h = einsum(x1,fk)/12 + b  -> LN -> FFN(64->256->64)
// (+residual layer1) -> x_new (layer0) and readout accumulation.
// Lane owns one ROW: all per-row state in registers, weights uniform from LDS.
// LDS: W1^T (t-major) + W2^T (c-major) = 128 KiB -> 1 block/CU.
// ---------------------------------------------------------------------------
__global__ __launch_bounds__(256) void node_kernel(
    const float* __restrict__ x1, const float* __restrict__ fk,
    const float* __restrict__ conv_b, const float* __restrict__ ln_g,
    const float* __restrict__ ln_b,
    const float* __restrict__ W1, const float* __restrict__ b1,
    const float* __restrict__ W2, const float* __restrict__ b2,
    const float* __restrict__ Wr, const float* __restrict__ br,
    const float* __restrict__ x_old, float* __restrict__ x_new,
    float* __restrict__ racc, int has_res, int write_x)
{
    __shared__ float sW1T[256*64];   // [t][k]
    __shared__ float sW2T[64*256];   // [c][t]
    for (int i = threadIdx.x; i < 16384; i += 256) {
        sW1T[(i & 255)*64 + (i >> 8)] = W1[i];   // W1[k][t] -> [t][k]
        sW2T[(i & 63)*256 + (i >> 6)] = W2[i];   // W2[t][c] -> [c][t]
    }
    __syncthreads();
    int lane = threadIdx.x & 63;
    int grp  = blockIdx.x*4 + (threadIdx.x >> 6);
    int row  = grp*64 + lane;
    if (row >= N_NODES * N_ORI) return;          // whole trailing wave exits
    int v = row / 12, p = row % 12;

    float h[64];
    #pragma unroll
    for (int k = 0; k < 64; k++) h[k] = 0.f;
    const float* xv = x1 + (size_t)v*768;
    const float* fp = fk + (size_t)p*768;
    for (int o = 0; o < 12; o++) {
        const float4* xa = (const float4*)(xv + o*64);
        const float4* fa = (const float4*)(fp + o*64);
        #pragma unroll
        for (int k4 = 0; k4 < 16; k4++) {
            float4 xd = xa[k4]; float4 fd = fa[k4];
            h[4*k4+0] += xd.x*fd.x; h[4*k4+1] += xd.y*fd.y;
            h[4*k4+2] += xd.z*fd.z; h[4*k4+3] += xd.w*fd.w;
        }
    }
    const float inv12 = 1.0f/12.0f;
    float mu = 0.f;
    #pragma unroll
    for (int k = 0; k < 64; k++) { h[k] = h[k]*inv12 + conv_b[k]; mu += h[k]; }
    mu *= (1.0f/64.0f);
    float var = 0.f;
    #pragma unroll
    for (int k = 0; k < 64; k++) { float xc = h[k] - mu; var += xc*xc; }
    var *= (1.0f/64.0f);
    float rstd = rsqrtf(var + 1e-5f);
    #pragma unroll
    for (int k = 0; k < 64; k++) h[k] = (h[k] - mu)*rstd*ln_g[k] + ln_b[k];

    float outv[64];
    #pragma unroll
    for (int k = 0; k < 64; k++) outv[k] = b2[k];
    for (int ch = 0; ch < 8; ch++) {             // 8 chunks of 32 hidden units
        float hid[32];
        #pragma unroll
        for (int j = 0; j < 32; j++) {
            int t = ch*32 + j;
            const float4* wr = (const float4*)(sW1T + t*64);
            float a = b1[t];
            #pragma unroll
            for (int k4 = 0; k4 < 16; k4++) {
                float4 wv = wr[k4];
                a += h[4*k4]*wv.x + h[4*k4+1]*wv.y + h[4*k4+2]*wv.z + h[4*k4+3]*wv.w;
            }
            hid[j] = gelu_f(a);
        }
        #pragma unroll
        for (int c = 0; c < 64; c++) {
            const float4* w2r = (const float4*)(sW2T + c*256 + ch*32);
            float a = 0.f;
            #pragma unroll
            for (int j4 = 0; j4 < 8; j4++) {
                float4 wv = w2r[j4];
                a += hid[4*j4]*wv.x + hid[4*j4+1]*wv.y + hid[4*j4+2]*wv.z + hid[4*j4+3]*wv.w;
            }
            outv[c] += a;
        }
    }
    if (has_res) {
        const float* xo = x_old + (size_t)row*64;
        #pragma unroll
        for (int k = 0; k < 64; k++) outv[k] += xo[k];
    }
    if (write_x) {
        float* xn = x_new + (size_t)row*64;
        #pragma unroll
        for (int k = 0; k < 64; k++) xn[k] = outv[k];
    }
    float r0 = br[0], r1 = br[1];
    #pragma unroll
    for (int k = 0; k < 64; k++) { r0 += outv[k]*Wr[2*k]; r1 += outv[k]*Wr[2*k+1]; }
    racc[row*2 + 0] += r0;
    racc[row*2 + 1] += r1;
}

// ---------------------------------------------------------------------------
// K5: readout: rs/rv = racc/2 ; out_s += mean_p rs ; out_v += sum_o rv*ori/12
// ---------------------------------------------------------------------------
__global__ __launch_bounds__(256) void final_kernel(
    const float* __restrict__ racc, const float* __restrict__ ori,
    const int* __restrict__ batch, float* __restrict__ out)
{
    int v = blockIdx.x*256 + threadIdx.x;
    if (v >= N_NODES) return;
    float srs = 0.f, vx = 0.f, vy = 0.f, vz = 0.f;
    #pragma unroll
    for (int p = 0; p < 12; p++) {
        float r0 = racc[v*24 + 2*p], r1 = racc[v*24 + 2*p + 1];
        srs += r0;
        vx += r1*ori[3*p]; vy += r1*ori[3*p+1]; vz += r1*ori[3*p+2];
    }
    const float sc = 1.0f/24.0f;   // /2 layers, /12 orientations
    int g = batch[v];
    atomicAdd(&out[g], srs*sc);
    atomicAdd(&out[16 + g*3 + 0], vx*sc);
    atomicAdd(&out[16 + g*3 + 1], vy*sc);
    atomicAdd(&out[16 + g*3 + 2], vz*sc);
}

extern "C" void kernel_launch(void* const* d_in, const int* in_sizes, int n_in,
                              void* d_out, int out_size, void* d_ws, size_t ws_size,
                              hipStream_t stream) {
    const float* pos    = (const float*)d_in[0];
    const float* f      = (const float*)d_in[1];
    const float* ori    = (const float*)d_in[2];
    const int*   ei     = (const int*)  d_in[3];
    const int*   batch  = (const int*)  d_in[4];
    const float* Wb1    = (const float*)d_in[5];
    const float* bb1    = (const float*)d_in[6];
    const float* Wb2    = (const float*)d_in[7];
    const float* bb2    = (const float*)d_in[8];
    const float* Wo1    = (const float*)d_in[9];
    const float* bo1    = (const float*)d_in[10];
    const float* Wo2    = (const float*)d_in[11];
    const float* bo2    = (const float*)d_in[12];
    const float* We     = (const float*)d_in[13];
    const float* Wk     = (const float*)d_in[14];
    const float* Wf     = (const float*)d_in[15];
    const float* conv_b = (const float*)d_in[16];
    const float* ln_g   = (const float*)d_in[17];
    const float* ln_b   = (const float*)d_in[18];
    const float* W1     = (const float*)d_in[19];
    const float* b1     = (const float*)d_in[20];
    const float* W2     = (const float*)d_in[21];
    const float* b2     = (const float*)d_in[22];
    const float* Wr     = (const float*)d_in[23];
    const float* br     = (const float*)d_in[24];
    float* out = (float*)d_out;

    float* ws   = (float*)d_ws;
    float* xe   = ws;                       // 640,000
    float* xs1  = xe   + 640000;            // 7,680,000
    float* x1a  = xs1  + 7680000;           // 7,680,000
    float* racc = x1a  + 7680000;           // 240,000
    float* fkb  = racc + 240000;            // 18,432   (total ~65 MB)

    hipMemsetAsync(out,  0, 64*sizeof(float), stream);
    hipMemsetAsync(racc, 0, 240000*sizeof(float), stream);
    hipMemsetAsync(x1a,  0, 7680000*sizeof(float), stream);

    ori_kernel  <<<144,  64, 0, stream>>>(ori, Wo1, bo1, Wo2, bo2, Wf, fkb);
    embed_kernel<<<2500, 256, 0, stream>>>(f, We, xe);

    // layer 0
    edge_kernel <<<20000,256, 0, stream>>>(pos, ori, Wb1, bb1, Wb2, bb2,
                                           Wk, ei, xe, x1a, /*has_ori=*/0);
    node_kernel <<<469,  256, 0, stream>>>(x1a, fkb, conv_b, ln_g, ln_b,
                                           W1, b1, W2, b2, Wr, br,
                                           nullptr, xs1, racc, /*res=*/0, /*write=*/1);
    // layer 1
    hipMemsetAsync(x1a, 0, 7680000*sizeof(float), stream);
    edge_kernel <<<20000,256, 0, stream>>>(pos, ori, Wb1, bb1, Wb2, bb2,
                                           Wk + 4096, ei, xs1, x1a, /*has_ori=*/1);
    node_kernel <<<469,  256, 0, stream>>>(x1a, fkb + 9216, conv_b + 64, ln_g + 64, ln_b + 64,
                                           W1 + 16384, b1 + 256, W2 + 16384, b2 + 64,
                                           Wr + 128, br + 2,
                                           xs1, nullptr, racc, /*res=*/1, /*write=*/0);

    final_kernel<<<40,   256, 0, stream>>>(racc, ori, batch, out);
}

// Round 2
// 2084.011 us; speedup vs baseline: 1.3098x; 1.3098x over previous
//
#include <hip/hip_runtime.h>
#include <hip/hip_bf16.h>
#include <math.h>

#define N_NODES 10000
#define N_EDGES 80000
#define N_ORI   12

__device__ __forceinline__ float gelu_f(float x) {
    return 0.5f * x * (1.0f + erff(x * 0.70710678118654752440f));
}

// ---------------------------------------------------------------------------
// K0: transpose W1 (64x256 -> [t][k]) and W2 (256x64 -> [c][t]) per layer.
// ---------------------------------------------------------------------------
__global__ __launch_bounds__(256) void transpose_w(
    const float* __restrict__ W1, const float* __restrict__ W2,
    float* __restrict__ W1T, float* __restrict__ W2T)
{
    int l = blockIdx.x;
    const float* w1 = W1 + l*16384; float* w1t = W1T + l*16384;
    const float* w2 = W2 + l*16384; float* w2t = W2T + l*16384;
    for (int i = threadIdx.x; i < 16384; i += 256) {
        w1t[(i & 255)*64 + (i >> 8)] = w1[i];   // W1[k][t] -> W1T[t][k]
        w2t[(i & 63)*256 + (i >> 6)] = w2[i];   // W2[t][c] -> W2T[c][t]
    }
}

// ---------------------------------------------------------------------------
// K1: kb_ori MLP + fk[l][p][o][c] = (kb_ori @ Wf[l]).  144 blocks x 64.
// ---------------------------------------------------------------------------
__global__ __launch_bounds__(64) void ori_kernel(
    const float* __restrict__ ori, const float* __restrict__ Wo1,
    const float* __restrict__ bo1, const float* __restrict__ Wo2,
    const float* __restrict__ bo2, const float* __restrict__ Wf,
    float* __restrict__ fkb)
{
    __shared__ float sh[64];
    __shared__ float skb[64];
    int i = blockIdx.x / 12, j = blockIdx.x % 12;
    int lane = threadIdx.x;
    float s = ori[3*i]*ori[3*j] + ori[3*i+1]*ori[3*j+1] + ori[3*i+2]*ori[3*j+2];
    float p1 = s, p2 = s*s, p3 = p2*s, p4 = p3*s;
    float acc = bo1[lane] + p1*Wo1[lane] + p2*Wo1[64+lane] + p3*Wo1[128+lane] + p4*Wo1[192+lane];
    sh[lane] = gelu_f(acc);
    __syncthreads();
    float acc2 = bo2[lane];
    #pragma unroll
    for (int k = 0; k < 64; k++) acc2 += sh[k] * Wo2[k*64 + lane];
    skb[lane] = gelu_f(acc2);
    __syncthreads();
    for (int l = 0; l < 2; l++) {
        float a = 0.f;
        #pragma unroll
        for (int k = 0; k < 64; k++) a += skb[k] * Wf[l*4096 + k*64 + lane];
        fkb[l*9216 + i*768 + j*64 + lane] = a;
    }
}

// ---------------------------------------------------------------------------
// K2: x = f @ We
// ---------------------------------------------------------------------------
__global__ __launch_bounds__(256) void embed_kernel(
    const float* __restrict__ f, const float* __restrict__ We, float* __restrict__ xe)
{
    int v = blockIdx.x*4 + (threadIdx.x >> 6);
    int lane = threadIdx.x & 63;
    if (v >= N_NODES) return;
    float acc = 0.f;
    #pragma unroll
    for (int k = 0; k < 16; k++) acc += f[v*16 + k] * We[k*64 + lane];
    xe[v*64 + lane] = acc;
}

// ---------------------------------------------------------------------------
// K3: kb[e,o,c] = gelu(gelu(poly @ Wb1) @ Wb2) * env(d), stored bf16. ONCE.
// Wave per edge, lane = channel. Weight columns in VGPRs, wave-local LDS for
// the cross-lane hidden vector (no block barriers: slices are per-wave).
// ---------------------------------------------------------------------------
__global__ __launch_bounds__(256) void kb_kernel(
    const float* __restrict__ pos, const float* __restrict__ ori,
    const float* __restrict__ Wb1, const float* __restrict__ bb1,
    const float* __restrict__ Wb2, const float* __restrict__ bb2,
    const int* __restrict__ ei, __hip_bfloat16* __restrict__ kbb)
{
    __shared__ float sh1[4][64];
    int w = threadIdx.x >> 6, lane = threadIdx.x & 63;

    float wb1c[30], wb2c[64];
    #pragma unroll
    for (int k = 0; k < 30; k++) wb1c[k] = Wb1[k*64 + lane];
    #pragma unroll
    for (int k = 0; k < 64; k++) wb2c[k] = Wb2[k*64 + lane];
    float bb1l = bb1[lane], bb2l = bb2[lane];

    int e  = blockIdx.x*4 + w;
    int sn = ei[e], dn = ei[N_EDGES + e];
    float rx = pos[sn*3+0] - pos[dn*3+0];
    float ry = pos[sn*3+1] - pos[dn*3+1];
    float rz = pos[sn*3+2] - pos[dn*3+2];
    float d  = sqrtf(rx*rx + ry*ry + rz*rz);
    float u2 = d*d, u4 = u2*u2, u6 = u4*u2;
    float env = (d < 1.0f) ? (1.0f - 28.0f*u6 + 48.0f*u6*d - 21.0f*u6*u2) : 0.0f;
    __hip_bfloat16* kbrow = kbb + (size_t)e*768;

    for (int o = 0; o < N_ORI; o++) {
        float ox = ori[3*o], oy = ori[3*o+1], oz = ori[3*o+2];  // uniform s_load
        float a  = rx*ox + ry*oy + rz*oz;
        float qx = rx - a*ox, qy = ry - a*oy, qz = rz - a*oz;
        float b  = sqrtf(qx*qx + qy*qy + qz*qz);
        float acc = bb1l + a*wb1c[0] + b*wb1c[1];
        float c0 = a*a, c1 = a*b, c2 = b*a, c3 = b*b;
        acc += c0*wb1c[2] + c1*wb1c[3] + c2*wb1c[4] + c3*wb1c[5];
        float d0=c0*a,d1=c0*b,d2=c1*a,d3=c1*b,d4=c2*a,d5=c2*b,d6=c3*a,d7=c3*b;
        acc += d0*wb1c[6]+d1*wb1c[7]+d2*wb1c[8]+d3*wb1c[9]
             + d4*wb1c[10]+d5*wb1c[11]+d6*wb1c[12]+d7*wb1c[13];
        acc += d0*a*wb1c[14]+d0*b*wb1c[15]+d1*a*wb1c[16]+d1*b*wb1c[17]
             + d2*a*wb1c[18]+d2*b*wb1c[19]+d3*a*wb1c[20]+d3*b*wb1c[21]
             + d4*a*wb1c[22]+d4*b*wb1c[23]+d5*a*wb1c[24]+d5*b*wb1c[25]
             + d6*a*wb1c[26]+d6*b*wb1c[27]+d7*a*wb1c[28]+d7*b*wb1c[29];
        sh1[w][lane] = gelu_f(acc);
        __builtin_amdgcn_wave_barrier();            // wave-synchronous LDS
        float acc2 = bb2l;
        const float4* h4 = (const float4*)(&sh1[w][0]);
        #pragma unroll
        for (int k4 = 0; k4 < 16; k4++) {
            float4 hv = h4[k4];
            acc2 += hv.x*wb2c[4*k4] + hv.y*wb2c[4*k4+1] + hv.z*wb2c[4*k4+2] + hv.w*wb2c[4*k4+3];
        }
        __builtin_amdgcn_wave_barrier();
        kbrow[o*64 + lane] = __float2bfloat16(gelu_f(acc2) * env);
    }
}

// ---------------------------------------------------------------------------
// K4: per-layer scatter: msg = x[src] * (kb @ Wk[l]); atomicAdd into x1[dst].
// Wave per edge; Wk column in VGPRs; kb row broadcast via wave-local LDS.
// ---------------------------------------------------------------------------
__global__ __launch_bounds__(256) void scatter_kernel(
    const __hip_bfloat16* __restrict__ kbb, const float* __restrict__ Wk,
    const int* __restrict__ ei, const float* __restrict__ x_in,
    float* __restrict__ x1, int has_ori)
{
    __shared__ float skb[4][64];
    int w = threadIdx.x >> 6, lane = threadIdx.x & 63;
    float wkc[64];
    #pragma unroll
    for (int k = 0; k < 64; k++) wkc[k] = Wk[k*64 + lane];

    int e  = blockIdx.x*4 + w;
    int sn = ei[e], dn = ei[N_EDGES + e];
    const __hip_bfloat16* kbrow = kbb + (size_t)e*768;
    const float* xsrc  = x_in + (has_ori ? (size_t)sn*768 : (size_t)sn*64);
    float*       x1row = x1 + (size_t)dn*768;
    float xs0 = has_ori ? 0.f : xsrc[lane];

    for (int o = 0; o < N_ORI; o++) {
        skb[w][lane] = __bfloat162float(kbrow[o*64 + lane]);
        __builtin_amdgcn_wave_barrier();
        float accm = 0.f;
        const float4* kb4 = (const float4*)(&skb[w][0]);
        #pragma unroll
        for (int k4 = 0; k4 < 16; k4++) {
            float4 kv = kb4[k4];
            accm += kv.x*wkc[4*k4] + kv.y*wkc[4*k4+1] + kv.z*wkc[4*k4+2] + kv.w*wkc[4*k4+3];
        }
        __builtin_amdgcn_wave_barrier();
        float xs = has_ori ? xsrc[o*64 + lane] : xs0;
        atomicAdd(&x1row[o*64 + lane], xs * accm);
    }
}

// ---------------------------------------------------------------------------
// K5: per-row conv-contract + LN + FFN (+res) + readout. Lane owns a row.
// Weights read with wave-uniform global indices -> scalar loads, no LDS.
// ---------------------------------------------------------------------------
__global__ __launch_bounds__(256) void node_kernel(
    const float* __restrict__ x1, const float* __restrict__ fk,
    const float* __restrict__ conv_b, const float* __restrict__ ln_g,
    const float* __restrict__ ln_b,
    const float* __restrict__ W1T, const float* __restrict__ b1,
    const float* __restrict__ W2T, const float* __restrict__ b2,
    const float* __restrict__ Wr, const float* __restrict__ br,
    const float* __restrict__ x_old, float* __restrict__ x_new,
    float* __restrict__ racc, int has_res, int write_x)
{
    int lane = threadIdx.x & 63;
    int grp  = blockIdx.x*4 + (threadIdx.x >> 6);
    int row  = grp*64 + lane;
    if (row >= N_NODES * N_ORI) return;
    int v = row / 12, p = row % 12;

    float h[64];
    #pragma unroll
    for (int k = 0; k < 64; k++) h[k] = 0.f;
    const float* xv = x1 + (size_t)v*768;
    const float* fp = fk + (size_t)p*768;
    for (int o = 0; o < 12; o++) {
        const float4* xa = (const float4*)(xv + o*64);
        const float4* fa = (const float4*)(fp + o*64);
        #pragma unroll
        for (int k4 = 0; k4 < 16; k4++) {
            float4 xd = xa[k4]; float4 fd = fa[k4];
            h[4*k4+0] += xd.x*fd.x; h[4*k4+1] += xd.y*fd.y;
            h[4*k4+2] += xd.z*fd.z; h[4*k4+3] += xd.w*fd.w;
        }
    }
    const float inv12 = 1.0f/12.0f;
    float mu = 0.f;
    #pragma unroll
    for (int k = 0; k < 64; k++) { h[k] = h[k]*inv12 + conv_b[k]; mu += h[k]; }
    mu *= (1.0f/64.0f);
    float var = 0.f;
    #pragma unroll
    for (int k = 0; k < 64; k++) { float xc = h[k] - mu; var += xc*xc; }
    var *= (1.0f/64.0f);
    float rstd = rsqrtf(var + 1e-5f);
    #pragma unroll
    for (int k = 0; k < 64; k++) h[k] = (h[k] - mu)*rstd*ln_g[k] + ln_b[k];

    float outv[64];
    #pragma unroll
    for (int k = 0; k < 64; k++) outv[k] = b2[k];
    for (int ch = 0; ch < 8; ch++) {
        float hid[32];
        #pragma unroll
        for (int j = 0; j < 32; j++) {
            int t = ch*32 + j;
            const float4* wr = (const float4*)(W1T + t*64);     // uniform -> s_load
            float a = b1[t];
            #pragma unroll
            for (int k4 = 0; k4 < 16; k4++) {
                float4 wv = wr[k4];
                a += h[4*k4]*wv.x + h[4*k4+1]*wv.y + h[4*k4+2]*wv.z + h[4*k4+3]*wv.w;
            }
            hid[j] = gelu_f(a);
        }
        #pragma unroll
        for (int c = 0; c < 64; c++) {
            const float4* w2r = (const float4*)(W2T + c*256 + ch*32);  // uniform
            float a = 0.f;
            #pragma unroll
            for (int j4 = 0; j4 < 8; j4++) {
                float4 wv = w2r[j4];
                a += hid[4*j4]*wv.x + hid[4*j4+1]*wv.y + hid[4*j4+2]*wv.z + hid[4*j4+3]*wv.w;
            }
            outv[c] += a;
        }
    }
    if (has_res) {
        const float* xo = x_old + (size_t)row*64;
        #pragma unroll
        for (int k = 0; k < 64; k++) outv[k] += xo[k];
    }
    if (write_x) {
        float* xn = x_new + (size_t)row*64;
        #pragma unroll
        for (int k = 0; k < 64; k++) xn[k] = outv[k];
    }
    float r0 = br[0], r1 = br[1];
    #pragma unroll
    for (int k = 0; k < 64; k++) { r0 += outv[k]*Wr[2*k]; r1 += outv[k]*Wr[2*k+1]; }
    racc[row*2 + 0] += r0;
    racc[row*2 + 1] += r1;
}

// ---------------------------------------------------------------------------
// K6: readout
// ---------------------------------------------------------------------------
__global__ __launch_bounds__(256) void final_kernel(
    const float* __restrict__ racc, const float* __restrict__ ori,
    const int* __restrict__ batch, float* __restrict__ out)
{
    int v = blockIdx.x*256 + threadIdx.x;
    if (v >= N_NODES) return;
    float srs = 0.f, vx = 0.f, vy = 0.f, vz = 0.f;
    #pragma unroll
    for (int p = 0; p < 12; p++) {
        float r0 = racc[v*24 + 2*p], r1 = racc[v*24 + 2*p + 1];
        srs += r0;
        vx += r1*ori[3*p]; vy += r1*ori[3*p+1]; vz += r1*ori[3*p+2];
    }
    const float sc = 1.0f/24.0f;
    int g = batch[v];
    atomicAdd(&out[g], srs*sc);
    atomicAdd(&out[16 + g*3 + 0], vx*sc);
    atomicAdd(&out[16 + g*3 + 1], vy*sc);
    atomicAdd(&out[16 + g*3 + 2], vz*sc);
}

extern "C" void kernel_launch(void* const* d_in, const int* in_sizes, int n_in,
                              void* d_out, int out_size, void* d_ws, size_t ws_size,
                              hipStream_t stream) {
    const float* pos    = (const float*)d_in[0];
    const float* f      = (const float*)d_in[1];
    const float* ori    = (const float*)d_in[2];
    const int*   ei     = (const int*)  d_in[3];
    const int*   batch  = (const int*)  d_in[4];
    const float* Wb1    = (const float*)d_in[5];
    const float* bb1    = (const float*)d_in[6];
    const float* Wb2    = (const float*)d_in[7];
    const float* bb2    = (const float*)d_in[8];
    const float* Wo1    = (const float*)d_in[9];
    const float* bo1    = (const float*)d_in[10];
    const float* Wo2    = (const float*)d_in[11];
    const float* bo2    = (const float*)d_in[12];
    const float* We     = (const float*)d_in[13];
    const float* Wk     = (const float*)d_in[14];
    const float* Wf     = (const float*)d_in[15];
    const float* conv_b = (const float*)d_in[16];
    const float* ln_g   = (const float*)d_in[17];
    const float* ln_b   = (const float*)d_in[18];
    const float* W1     = (const float*)d_in[19];
    const float* b1     = (const float*)d_in[20];
    const float* W2     = (const float*)d_in[21];
    const float* b2     = (const float*)d_in[22];
    const float* Wr     = (const float*)d_in[23];
    const float* br     = (const float*)d_in[24];
    float* out = (float*)d_out;

    float* ws   = (float*)d_ws;
    float* xe   = ws;                       //   640,000 f32
    float* xs1  = xe   + 640000;            // 7,680,000
    float* x1a  = xs1  + 7680000;           // 7,680,000
    float* racc = x1a  + 7680000;           //   240,000
    float* fkb  = racc + 240000;            //    18,432
    float* w1t  = fkb  + 18432;             //    32,768 (2 layers)
    float* w2t  = w1t  + 32768;             //    32,768
    __hip_bfloat16* kbb = (__hip_bfloat16*)(w2t + 32768);   // 61,440,000 bf16 (~123 MB)

    hipMemsetAsync(out,  0, 64*sizeof(float), stream);
    hipMemsetAsync(racc, 0, 240000*sizeof(float), stream);
    hipMemsetAsync(x1a,  0, 7680000*sizeof(float), stream);

    transpose_w <<<2,    256, 0, stream>>>(W1, W2, w1t, w2t);
    ori_kernel  <<<144,  64, 0, stream>>>(ori, Wo1, bo1, Wo2, bo2, Wf, fkb);
    embed_kernel<<<2500, 256, 0, stream>>>(f, We, xe);
    kb_kernel   <<<20000,256, 0, stream>>>(pos, ori, Wb1, bb1, Wb2, bb2, ei, kbb);

    // layer 0
    scatter_kernel<<<20000,256, 0, stream>>>(kbb, Wk, ei, xe, x1a, /*has_ori=*/0);
    node_kernel   <<<469,  256, 0, stream>>>(x1a, fkb, conv_b, ln_g, ln_b,
                                             w1t, b1, w2t, b2, Wr, br,
                                             nullptr, xs1, racc, /*res=*/0, /*write=*/1);
    // layer 1
    hipMemsetAsync(x1a, 0, 7680000*sizeof(float), stream);
    scatter_kernel<<<20000,256, 0, stream>>>(kbb, Wk + 4096, ei, xs1, x1a, /*has_ori=*/1);
    node_kernel   <<<469,  256, 0, stream>>>(x1a, fkb + 9216, conv_b + 64, ln_g + 64, ln_b + 64,
                                             w1t + 16384, b1 + 256, w2t + 16384, b2 + 64,
                                             Wr + 128, br + 2,
                                             xs1, nullptr, racc, /*res=*/1, /*write=*/0);

    final_kernel<<<40,   256, 0, stream>>>(racc, ori, batch, out);
}